// Round 2
// baseline (519.249 us; speedup 1.0000x reference)
//
#include <hip/hip_runtime.h>
#include <math.h>

#define NROWS 1024      // B*P
#define K1    12544
#define REP   1024
#define NDET  2048      // P*(C-1)
#define DETS  100
#define BBOX_CLIP_F 4.135166556742356f

// ---------------- GEMM: C_part[z] = A[:, z-chunk] @ W[z-chunk, :] ----------------
// A: [1024 x K] row-major, W: [K x 1024] row-major, T: [4][1024][1024]
__global__ __launch_bounds__(256) void gemm64(
    const float* __restrict__ A, const float* __restrict__ W,
    float* __restrict__ T, int K, int N, int kChunk) {
  __shared__ float As[32][68];   // K-major, padded: 16B-aligned b128 fragments
  __shared__ float Bs[32][64];
  const int tid = threadIdx.x;
  const int bm = blockIdx.x * 64, bn = blockIdx.y * 64;
  const int k0 = blockIdx.z * kChunk;
  const int tx = tid & 15, ty = tid >> 4;
  const int ar = tid >> 3;            // 0..31
  const int ac = (tid & 7) << 2;      // 0,4,..,28
  const int br = tid >> 4;            // 0..15
  const int bc = (tid & 15) << 2;     // 0..60
  float acc[4][4] = {{0.f,0.f,0.f,0.f},{0.f,0.f,0.f,0.f},{0.f,0.f,0.f,0.f},{0.f,0.f,0.f,0.f}};
  for (int kk = k0; kk < k0 + kChunk; kk += 32) {
    float4 a0 = *(const float4*)&A[(size_t)(bm + ar) * K + kk + ac];
    float4 a1 = *(const float4*)&A[(size_t)(bm + ar + 32) * K + kk + ac];
    float4 b0 = *(const float4*)&W[(size_t)(kk + br) * N + bn + bc];
    float4 b1 = *(const float4*)&W[(size_t)(kk + br + 16) * N + bn + bc];
    As[ac+0][ar] = a0.x; As[ac+1][ar] = a0.y; As[ac+2][ar] = a0.z; As[ac+3][ar] = a0.w;
    As[ac+0][ar+32] = a1.x; As[ac+1][ar+32] = a1.y; As[ac+2][ar+32] = a1.z; As[ac+3][ar+32] = a1.w;
    *(float4*)&Bs[br][bc]    = b0;
    *(float4*)&Bs[br+16][bc] = b1;
    __syncthreads();
#pragma unroll
    for (int k = 0; k < 32; ++k) {
      float4 av = *(const float4*)&As[k][ty << 2];
      float4 bv = *(const float4*)&Bs[k][tx << 2];
      float a_[4] = {av.x, av.y, av.z, av.w};
      float b_[4] = {bv.x, bv.y, bv.z, bv.w};
#pragma unroll
      for (int i = 0; i < 4; ++i)
#pragma unroll
        for (int j = 0; j < 4; ++j)
          acc[i][j] = fmaf(a_[i], b_[j], acc[i][j]);
    }
    __syncthreads();
  }
  float* Tz = T + (size_t)blockIdx.z * NROWS * REP;
#pragma unroll
  for (int i = 0; i < 4; ++i) {
    float4 v = make_float4(acc[i][0], acc[i][1], acc[i][2], acc[i][3]);
    *(float4*)&Tz[(size_t)(bm + (ty << 2) + i) * N + bn + (tx << 2)] = v;
  }
}

// H = relu(T0+T1+T2+T3 + bias)
__global__ __launch_bounds__(256) void combine_relu(
    const float* __restrict__ T, const float* __restrict__ bias, float* __restrict__ H) {
  const int i = blockIdx.x * 256 + threadIdx.x;          // float4 index
  const int MN4 = NROWS * REP / 4;
  const float4* t = (const float4*)T;
  float4 a = t[i], b = t[i + MN4], c = t[i + 2 * MN4], d = t[i + 3 * MN4];
  float4 bs = ((const float4*)bias)[i & 255];
  float4 r;
  r.x = fmaxf(((a.x + b.x) + (c.x + d.x)) + bs.x, 0.f);
  r.y = fmaxf(((a.y + b.y) + (c.y + d.y)) + bs.y, 0.f);
  r.z = fmaxf(((a.z + b.z) + (c.z + d.z)) + bs.z, 0.f);
  r.w = fmaxf(((a.w + b.w) + (c.w + d.w)) + bs.w, 0.f);
  ((float4*)H)[i] = r;
}

// Per proposal row: 25 head outputs, softmax, decode+clip, scatter to pb/sc
__global__ __launch_bounds__(256) void heads_kernel(
    const float* __restrict__ H2, const float* __restrict__ Wc, const float* __restrict__ bcv,
    const float* __restrict__ Wb, const float* __restrict__ bbv,
    const float* __restrict__ props, float* __restrict__ pb, float* __restrict__ sc) {
  const int n = blockIdx.x;
  __shared__ float hrow[REP];
  __shared__ float part[25][8];
  __shared__ float outv[25];
  __shared__ float smax[5];
  const int tid = threadIdx.x;
  ((float4*)hrow)[tid] = ((const float4*)(H2 + (size_t)n * REP))[tid];
  __syncthreads();
  if (tid < 200) {
    const int o = tid >> 3, s = tid & 7;
    float a = 0.f;
    if (o < 5) {
      const float* w = Wc + o;
      for (int k = s * 128; k < s * 128 + 128; ++k) a = fmaf(hrow[k], w[(size_t)k * 5], a);
    } else {
      const float* w = Wb + (o - 5);
      for (int k = s * 128; k < s * 128 + 128; ++k) a = fmaf(hrow[k], w[(size_t)k * 20], a);
    }
    part[o][s] = a;
  }
  __syncthreads();
  if (tid < 25) {
    float a = ((part[tid][0] + part[tid][1]) + (part[tid][2] + part[tid][3]))
            + ((part[tid][4] + part[tid][5]) + (part[tid][6] + part[tid][7]));
    a += (tid < 5) ? bcv[tid] : bbv[tid - 5];
    outv[tid] = a;
  }
  __syncthreads();
  if (tid == 0) {
    float m = outv[0];
    for (int c = 1; c < 5; ++c) m = fmaxf(m, outv[c]);
    float e[5], ssum = 0.f;
    for (int c = 0; c < 5; ++c) { e[c] = expf(outv[c] - m); ssum += e[c]; }
    for (int c = 0; c < 5; ++c) smax[c] = e[c] / ssum;
  }
  __syncthreads();
  if (tid < 4) {
    const int c = tid + 1;
    const float* pr = props + (size_t)n * 4;
    const float x1 = pr[0], y1 = pr[1], x2 = pr[2], y2 = pr[3];
    const float w = x2 - x1, h = y2 - y1;
    const float cx = x1 + 0.5f * w, cy = y1 + 0.5f * h;
    const float r0 = outv[5 + c * 4 + 0], r1 = outv[5 + c * 4 + 1];
    const float r2 = outv[5 + c * 4 + 2], r3 = outv[5 + c * 4 + 3];
    const float dx = r0 / 10.0f, dy = r1 / 10.0f;
    const float dw = fminf(r2 / 5.0f, BBOX_CLIP_F);
    const float dh = fminf(r3 / 5.0f, BBOX_CLIP_F);
    const float pcx = dx * w + cx, pcy = dy * h + cy;
    const float pw = expf(dw) * w, ph = expf(dh) * h;
    float bx1 = pcx - 0.5f * pw, by1 = pcy - 0.5f * ph;
    float bx2 = pcx + 0.5f * pw, by2 = pcy + 0.5f * ph;
    bx1 = fminf(fmaxf(bx1, 0.f), 800.f);
    by1 = fminf(fmaxf(by1, 0.f), 800.f);
    bx2 = fminf(fmaxf(bx2, 0.f), 800.f);
    by2 = fminf(fmaxf(by2, 0.f), 800.f);
    const int img = n >> 9;
    const int pidx = ((n & 511) << 2) + (c - 1);
    float* o = pb + (size_t)(img * NDET + pidx) * 4;
    o[0] = bx1; o[1] = by1; o[2] = bx2; o[3] = by2;
    sc[img * NDET + pidx] = smax[c];
  }
}

// Stable descending sort of 2048 scores per image (bitonic on u64 composite key)
__global__ __launch_bounds__(1024) void sort_kernel(
    const float* __restrict__ sc, unsigned* __restrict__ sidx) {
  const int b = blockIdx.x;
  __shared__ unsigned long long key[NDET];
  const int tid = threadIdx.x;
  for (int t = tid; t < NDET; t += 1024) {
    unsigned bits = __float_as_uint(sc[b * NDET + t]);   // scores > 0 -> monotonic
    key[t] = ((unsigned long long)bits << 32) | (unsigned)(~t);
  }
  __syncthreads();
  for (int k = 2; k <= NDET; k <<= 1) {
    for (int j = k >> 1; j > 0; j >>= 1) {
      for (int t = tid; t < NDET; t += 1024) {
        const int ixj = t ^ j;
        if (ixj > t) {
          const bool up = (t & k) == 0;
          unsigned long long a = key[t], bb_ = key[ixj];
          if ((a < bb_) == up) { key[t] = bb_; key[ixj] = a; }  // descending overall
        }
      }
      __syncthreads();
    }
  }
  for (int t = tid; t < NDET; t += 1024)
    sidx[b * NDET + t] = ~(unsigned)key[t];
}

// Gather into sorted order; compute valid bits, offset boxes, areas, labels
__global__ __launch_bounds__(256) void prep_kernel(
    const unsigned* __restrict__ sidx, const float* __restrict__ pb, const float* __restrict__ sc,
    float* __restrict__ sbox, float* __restrict__ soff, float* __restrict__ sscore,
    float* __restrict__ sarea, float* __restrict__ slab, unsigned* __restrict__ vword) {
  const int b = blockIdx.y;
  const int i = blockIdx.x * 256 + threadIdx.x;
  const unsigned oi = sidx[b * NDET + i];
  const float* bx = pb + (size_t)(b * NDET + oi) * 4;
  const float x1 = bx[0], y1 = bx[1], x2 = bx[2], y2 = bx[3];
  const float s = sc[b * NDET + oi];
  const float lab = (float)((oi & 3) + 1);
  const bool valid = (s > 0.05f) && ((x2 - x1) >= 0.01f) && ((y2 - y1) >= 0.01f);
  const float off = lab * 801.0f;
  float* sb = sbox + (size_t)(b * NDET + i) * 4;
  sb[0] = x1; sb[1] = y1; sb[2] = x2; sb[3] = y2;
  float* so = soff + (size_t)(b * NDET + i) * 4;
  so[0] = x1 + off; so[1] = y1 + off; so[2] = x2 + off; so[3] = y2 + off;
  sscore[b * NDET + i] = s;
  sarea[b * NDET + i] = (x2 - x1) * (y2 - y1);
  slab[b * NDET + i] = lab;
  const unsigned long long bal = __ballot(valid);
  if ((i & 31) == 0) vword[b * 64 + (i >> 5)] = (unsigned)(bal >> (i & 32));
}

// Suppression bitmask: word w of row i, bit jj  <->  j = jj*64 + w  (scan-lane layout)
__global__ __launch_bounds__(256) void mask_kernel(
    const float* __restrict__ soff, const float* __restrict__ sarea,
    unsigned* __restrict__ mask) {
  const int b = blockIdx.y;
  __shared__ float box[NDET][4];
  __shared__ float area[NDET];
  const int tid = threadIdx.x;
  const float4* src = (const float4*)(soff + (size_t)b * NDET * 4);
  for (int t = tid; t < NDET; t += 256) ((float4*)box)[t] = src[t];
  const float4* asrc = (const float4*)(sarea + (size_t)b * NDET);
  for (int t = tid; t < NDET / 4; t += 256) ((float4*)area)[t] = asrc[t];
  __syncthreads();
  const int li = tid >> 6;            // 0..3
  const int w  = tid & 63;            // 0..63
  const int i  = blockIdx.x * 4 + li;
  const float ax1 = box[i][0], ay1 = box[i][1], ax2 = box[i][2], ay2 = box[i][3];
  const float aa = area[i];
  unsigned bits = 0;
#pragma unroll 4
  for (int jj = 0; jj < 32; ++jj) {
    const int j = jj * 64 + w;        // lanes read consecutive rows: conflict-free
    const float ix = fmaxf(fminf(ax2, box[j][2]) - fmaxf(ax1, box[j][0]), 0.f);
    const float iy = fmaxf(fminf(ay2, box[j][3]) - fmaxf(ay1, box[j][1]), 0.f);
    const float inter = ix * iy;
    const float iou = inter / (aa + area[j] - inter + 1e-9f);
    if (j > i && iou > 0.5f) bits |= (1u << jj);
  }
  mask[((size_t)b * NDET + i) * 64 + w] = bits;
}

// Single-wave greedy scan with register-resident suppression mask; early-exit at 100 kept
__global__ __launch_bounds__(64) void scan_kernel(
    const unsigned* __restrict__ vword, const unsigned* __restrict__ mask,
    const float* __restrict__ sbox, const float* __restrict__ sscore,
    const float* __restrict__ slab, float* __restrict__ out) {
  const int b = blockIdx.x;
  const int lane = threadIdx.x;
  const unsigned valid = vword[b * 64 + lane];
  unsigned sup = 0;                    // bit jj of lane l  <->  j = jj*64 + l
  __shared__ unsigned short klist[DETS];
  int kcnt = 0;
  for (int i = 0; i < NDET; ++i) {
    const unsigned v = __shfl(valid, i >> 5);
    if (!((v >> (i & 31)) & 1)) continue;
    const unsigned s = __shfl(sup, i & 63);
    if ((s >> (i >> 6)) & 1) continue;
    if (lane == 0) klist[kcnt] = (unsigned short)i;
    kcnt++;
    sup |= mask[((size_t)b * NDET + i) * 64 + lane];
    if (kcnt == DETS) break;
  }
  __syncthreads();
  for (int s = lane; s < DETS; s += 64) {
    float b0 = 0.f, b1 = 0.f, b2 = 0.f, b3 = 0.f, sv = 0.f, lv = 0.f;
    if (s < kcnt) {
      const int i = klist[s];
      const float* bx = sbox + ((size_t)b * NDET + i) * 4;
      b0 = bx[0]; b1 = bx[1]; b2 = bx[2]; b3 = bx[3];
      sv = sscore[b * NDET + i];
      lv = slab[b * NDET + i];
    }
    float* ob = out + ((size_t)b * DETS + s) * 4;
    ob[0] = b0; ob[1] = b1; ob[2] = b2; ob[3] = b3;
    out[2 * DETS * 4 + b * DETS + s] = sv;             // scores block
    out[2 * DETS * 4 + 2 * DETS + b * DETS + s] = lv;  // labels block (as float)
  }
}

extern "C" void kernel_launch(void* const* d_in, const int* in_sizes, int n_in,
                              void* d_out, int out_size, void* d_ws, size_t ws_size,
                              hipStream_t stream) {
  const float* X     = (const float*)d_in[0];
  const float* props = (const float*)d_in[1];
  const float* W1    = (const float*)d_in[2];
  const float* b1    = (const float*)d_in[3];
  const float* W2    = (const float*)d_in[4];
  const float* b2    = (const float*)d_in[5];
  const float* Wc    = (const float*)d_in[6];
  const float* bc    = (const float*)d_in[7];
  const float* Wb    = (const float*)d_in[8];
  const float* bb    = (const float*)d_in[9];
  float* out = (float*)d_out;

  float* fws = (float*)d_ws;
  float* T  = fws;                       // 4 * 1024*1024
  float* H1 = T + 4 * 1048576;           // 1024*1024
  float* H2 = H1 + 1048576;              // 1024*1024
  float* pb = H2 + 1048576;              // 2*2048*4
  float* sc = pb + 2 * NDET * 4;         // 2*2048
  unsigned* sidx = (unsigned*)(sc + 2 * NDET);     // 2*2048
  float* sbox   = (float*)(sidx + 2 * NDET);       // 2*2048*4
  float* soff   = sbox + 2 * NDET * 4;             // 2*2048*4
  float* sscore = soff + 2 * NDET * 4;             // 2*2048
  float* sarea  = sscore + 2 * NDET;               // 2*2048
  float* slab   = sarea + 2 * NDET;                // 2*2048
  unsigned* vword = (unsigned*)(slab + 2 * NDET);  // 2*64
  unsigned* mask  = vword + 128;                   // 2*2048*64

  // MLP: two GEMMs, each split-K=4 for occupancy (1024 blocks = 4/CU)
  gemm64<<<dim3(16, 16, 4), 256, 0, stream>>>(X, W1, T, K1, REP, K1 / 4);
  combine_relu<<<1024, 256, 0, stream>>>(T, b1, H1);
  gemm64<<<dim3(16, 16, 4), 256, 0, stream>>>(H1, W2, T, REP, REP, REP / 4);
  combine_relu<<<1024, 256, 0, stream>>>(T, b2, H2);
  // predictor + decode + clip + softmax
  heads_kernel<<<1024, 256, 0, stream>>>(H2, Wc, bc, Wb, bb, props, pb, sc);
  // per-image postprocess
  sort_kernel<<<2, 1024, 0, stream>>>(sc, sidx);
  prep_kernel<<<dim3(8, 2), 256, 0, stream>>>(sidx, pb, sc, sbox, soff, sscore, sarea, slab, vword);
  mask_kernel<<<dim3(512, 2), 256, 0, stream>>>(soff, sarea, mask);
  scan_kernel<<<2, 64, 0, stream>>>(vword, mask, sbox, sscore, slab, out);
}

// Round 3
// 263.078 us; speedup vs baseline: 1.9737x; 1.9737x over previous
//
#include <hip/hip_runtime.h>
#include <math.h>

#define NROWS 1024      // B*P
#define K1    12544
#define REP   1024
#define NDET  2048      // P*(C-1)
#define DETS  100
#define BBOX_CLIP_F 4.135166556742356f
#define LDA   40        // padded LDS stride (ushorts) for 32-k bf16 tiles

typedef __attribute__((ext_vector_type(8))) short bf16x8;
typedef __attribute__((ext_vector_type(4))) float f32x4;

__device__ __forceinline__ unsigned short rne_bf16(float x) {
  unsigned u = __float_as_uint(x);
  u += 0x7fffu + ((u >> 16) & 1u);
  return (unsigned short)(u >> 16);
}
__device__ __forceinline__ float bf16f(unsigned short h) {
  return __uint_as_float(((unsigned)h) << 16);
}

// ---------- transpose + fp32->bf16 hi/lo convert: W[K][N] -> WT{h,l}[N][K] ----------
__global__ __launch_bounds__(256) void transpose_bf16(
    const float* __restrict__ W, unsigned short* __restrict__ WTh,
    unsigned short* __restrict__ WTl, int K, int N) {
  __shared__ unsigned short th[32 * 36], tl[32 * 36];
  const int k0 = blockIdx.x * 32, n0 = blockIdx.y * 32;
  const int t = threadIdx.x;
  const int r = t >> 3, c4 = (t & 7) << 2;
  float4 v = *(const float4*)&W[(size_t)(k0 + r) * N + n0 + c4];
  float fv[4] = {v.x, v.y, v.z, v.w};
#pragma unroll
  for (int j = 0; j < 4; ++j) {
    unsigned short h = rne_bf16(fv[j]);
    th[(c4 + j) * 36 + r] = h;
    tl[(c4 + j) * 36 + r] = rne_bf16(fv[j] - bf16f(h));
  }
  __syncthreads();
  ushort4 oh = *(ushort4*)&th[r * 36 + c4];
  ushort4 ol = *(ushort4*)&tl[r * 36 + c4];
  *(ushort4*)&WTh[(size_t)(n0 + r) * K + k0 + c4] = oh;
  *(ushort4*)&WTl[(size_t)(n0 + r) * K + k0 + c4] = ol;
}

// ---------- MFMA GEMM: T[z] += A[M,K]fp32 (hi/lo split) @ B (BT{h,l}[N][K] bf16) ----------
// 128x128 tile, 4 waves (each 64x64 via 4x4 16x16x32 frags), BK=32, reg-staged conversion.
__global__ __launch_bounds__(256) void gemm_mfma(
    const float* __restrict__ A, const unsigned short* __restrict__ BTh,
    const unsigned short* __restrict__ BTl, float* __restrict__ T,
    int K, int stepsPerZ) {
  __shared__ unsigned short Ash[128 * LDA], Asl[128 * LDA];
  __shared__ unsigned short Bsh[128 * LDA], Bsl[128 * LDA];
  const int tid = threadIdx.x;
  const int bm = blockIdx.x * 128, bn = blockIdx.y * 128;
  const int k0 = blockIdx.z * stepsPerZ * 32;
  const int w = tid >> 6, l = tid & 63;
  const int wr = (w >> 1) * 64, wc = (w & 1) * 64;
  const int fr = l & 15, fk = (l >> 4) * 8;
  const int srow = tid >> 2, skq = tid & 3;      // staging: 4 lanes/row, 64B segments
  f32x4 acc[4][4];
#pragma unroll
  for (int m = 0; m < 4; ++m)
#pragma unroll
    for (int n = 0; n < 4; ++n) acc[m][n] = (f32x4){0.f, 0.f, 0.f, 0.f};

  for (int s = 0; s < stepsPerZ; ++s) {
    const int kk = k0 + s * 32;
#pragma unroll
    for (int half = 0; half < 2; ++half) {
      const int row = srow + half * 64;
      // A: fp32 -> bf16 hi/lo (fused conversion)
      const float* ap = A + (size_t)(bm + row) * K + kk + skq * 8;
      float4 f0 = *(const float4*)ap;
      float4 f1 = *(const float4*)(ap + 4);
      float fv[8] = {f0.x, f0.y, f0.z, f0.w, f1.x, f1.y, f1.z, f1.w};
      unsigned hp[4], lp[4];
#pragma unroll
      for (int j = 0; j < 4; ++j) {
        unsigned short h0 = rne_bf16(fv[2 * j]), h1 = rne_bf16(fv[2 * j + 1]);
        float l0 = fv[2 * j] - bf16f(h0), l1 = fv[2 * j + 1] - bf16f(h1);
        hp[j] = (unsigned)h0 | ((unsigned)h1 << 16);
        lp[j] = (unsigned)rne_bf16(l0) | ((unsigned)rne_bf16(l1) << 16);
      }
      *(uint4*)&Ash[row * LDA + skq * 8] = make_uint4(hp[0], hp[1], hp[2], hp[3]);
      *(uint4*)&Asl[row * LDA + skq * 8] = make_uint4(lp[0], lp[1], lp[2], lp[3]);
      // B: already bf16 hi/lo, K-contiguous
      *(uint4*)&Bsh[row * LDA + skq * 8] =
          *(const uint4*)&BTh[(size_t)(bn + row) * K + kk + skq * 8];
      *(uint4*)&Bsl[row * LDA + skq * 8] =
          *(const uint4*)&BTl[(size_t)(bn + row) * K + kk + skq * 8];
    }
    __syncthreads();
    bf16x8 ah[4], al[4], bh[4], bl[4];
#pragma unroll
    for (int m = 0; m < 4; ++m) {
      ah[m] = *(const bf16x8*)&Ash[(wr + m * 16 + fr) * LDA + fk];
      al[m] = *(const bf16x8*)&Asl[(wr + m * 16 + fr) * LDA + fk];
    }
#pragma unroll
    for (int n = 0; n < 4; ++n) {
      bh[n] = *(const bf16x8*)&Bsh[(wc + n * 16 + fr) * LDA + fk];
      bl[n] = *(const bf16x8*)&Bsl[(wc + n * 16 + fr) * LDA + fk];
    }
#pragma unroll
    for (int m = 0; m < 4; ++m)
#pragma unroll
      for (int n = 0; n < 4; ++n) {
        acc[m][n] = __builtin_amdgcn_mfma_f32_16x16x32_bf16(ah[m], bh[n], acc[m][n], 0, 0, 0);
        acc[m][n] = __builtin_amdgcn_mfma_f32_16x16x32_bf16(ah[m], bl[n], acc[m][n], 0, 0, 0);
        acc[m][n] = __builtin_amdgcn_mfma_f32_16x16x32_bf16(al[m], bh[n], acc[m][n], 0, 0, 0);
      }
    __syncthreads();
  }
  // epilogue: D row = (l>>4)*4 + j, col = l&15  [guide-verified C/D layout]
  float* Tz = T + (size_t)blockIdx.z * (NROWS * REP);
#pragma unroll
  for (int m = 0; m < 4; ++m) {
    const int r0 = bm + wr + m * 16 + ((l >> 4) << 2);
#pragma unroll
    for (int n = 0; n < 4; ++n) {
      const int c = bn + wc + n * 16 + fr;
#pragma unroll
      for (int j = 0; j < 4; ++j) Tz[(size_t)(r0 + j) * REP + c] = acc[m][n][j];
    }
  }
}

// H = relu(sum_{z<8} T[z] + bias)
__global__ __launch_bounds__(256) void combine8_relu(
    const float* __restrict__ T, const float* __restrict__ bias, float* __restrict__ H) {
  const int i = blockIdx.x * 256 + threadIdx.x;
  const int MN4 = NROWS * REP / 4;
  const float4* t = (const float4*)T;
  float4 s0 = t[i];
#pragma unroll
  for (int z = 1; z < 8; ++z) {
    float4 v = t[i + z * MN4];
    s0.x += v.x; s0.y += v.y; s0.z += v.z; s0.w += v.w;
  }
  float4 bs = ((const float4*)bias)[i & 255];
  float4 r;
  r.x = fmaxf(s0.x + bs.x, 0.f);
  r.y = fmaxf(s0.y + bs.y, 0.f);
  r.z = fmaxf(s0.z + bs.z, 0.f);
  r.w = fmaxf(s0.w + bs.w, 0.f);
  ((float4*)H)[i] = r;
}

// ---------------- legacy fp32 GEMM (fallback when ws is small) ----------------
__global__ __launch_bounds__(256) void gemm64(
    const float* __restrict__ A, const float* __restrict__ W,
    float* __restrict__ T, int K, int N, int kChunk) {
  __shared__ float As[32][68];
  __shared__ float Bs[32][64];
  const int tid = threadIdx.x;
  const int bm = blockIdx.x * 64, bn = blockIdx.y * 64;
  const int k0 = blockIdx.z * kChunk;
  const int tx = tid & 15, ty = tid >> 4;
  const int ar = tid >> 3;
  const int ac = (tid & 7) << 2;
  const int br = tid >> 4;
  const int bc = (tid & 15) << 2;
  float acc[4][4] = {{0.f,0.f,0.f,0.f},{0.f,0.f,0.f,0.f},{0.f,0.f,0.f,0.f},{0.f,0.f,0.f,0.f}};
  for (int kk = k0; kk < k0 + kChunk; kk += 32) {
    float4 a0 = *(const float4*)&A[(size_t)(bm + ar) * K + kk + ac];
    float4 a1 = *(const float4*)&A[(size_t)(bm + ar + 32) * K + kk + ac];
    float4 b0 = *(const float4*)&W[(size_t)(kk + br) * N + bn + bc];
    float4 b1 = *(const float4*)&W[(size_t)(kk + br + 16) * N + bn + bc];
    As[ac+0][ar] = a0.x; As[ac+1][ar] = a0.y; As[ac+2][ar] = a0.z; As[ac+3][ar] = a0.w;
    As[ac+0][ar+32] = a1.x; As[ac+1][ar+32] = a1.y; As[ac+2][ar+32] = a1.z; As[ac+3][ar+32] = a1.w;
    *(float4*)&Bs[br][bc]    = b0;
    *(float4*)&Bs[br+16][bc] = b1;
    __syncthreads();
#pragma unroll
    for (int k = 0; k < 32; ++k) {
      float4 av = *(const float4*)&As[k][ty << 2];
      float4 bv = *(const float4*)&Bs[k][tx << 2];
      float a_[4] = {av.x, av.y, av.z, av.w};
      float b_[4] = {bv.x, bv.y, bv.z, bv.w};
#pragma unroll
      for (int i = 0; i < 4; ++i)
#pragma unroll
        for (int j = 0; j < 4; ++j)
          acc[i][j] = fmaf(a_[i], b_[j], acc[i][j]);
    }
    __syncthreads();
  }
  float* Tz = T + (size_t)blockIdx.z * NROWS * REP;
#pragma unroll
  for (int i = 0; i < 4; ++i) {
    float4 v = make_float4(acc[i][0], acc[i][1], acc[i][2], acc[i][3]);
    *(float4*)&Tz[(size_t)(bm + (ty << 2) + i) * N + bn + (tx << 2)] = v;
  }
}

// H = relu(T0+T1+T2+T3 + bias)
__global__ __launch_bounds__(256) void combine_relu(
    const float* __restrict__ T, const float* __restrict__ bias, float* __restrict__ H) {
  const int i = blockIdx.x * 256 + threadIdx.x;
  const int MN4 = NROWS * REP / 4;
  const float4* t = (const float4*)T;
  float4 a = t[i], b = t[i + MN4], c = t[i + 2 * MN4], d = t[i + 3 * MN4];
  float4 bs = ((const float4*)bias)[i & 255];
  float4 r;
  r.x = fmaxf(((a.x + b.x) + (c.x + d.x)) + bs.x, 0.f);
  r.y = fmaxf(((a.y + b.y) + (c.y + d.y)) + bs.y, 0.f);
  r.z = fmaxf(((a.z + b.z) + (c.z + d.z)) + bs.z, 0.f);
  r.w = fmaxf(((a.w + b.w) + (c.w + d.w)) + bs.w, 0.f);
  ((float4*)H)[i] = r;
}

// Per proposal row: 25 head outputs, softmax, decode+clip, scatter to pb/sc
__global__ __launch_bounds__(256) void heads_kernel(
    const float* __restrict__ H2, const float* __restrict__ Wc, const float* __restrict__ bcv,
    const float* __restrict__ Wb, const float* __restrict__ bbv,
    const float* __restrict__ props, float* __restrict__ pb, float* __restrict__ sc) {
  const int n = blockIdx.x;
  __shared__ float hrow[REP];
  __shared__ float part[25][8];
  __shared__ float outv[25];
  __shared__ float smax[5];
  const int tid = threadIdx.x;
  ((float4*)hrow)[tid] = ((const float4*)(H2 + (size_t)n * REP))[tid];
  __syncthreads();
  if (tid < 200) {
    const int o = tid >> 3, s = tid & 7;
    float a = 0.f;
    if (o < 5) {
      const float* w = Wc + o;
      for (int k = s * 128; k < s * 128 + 128; ++k) a = fmaf(hrow[k], w[(size_t)k * 5], a);
    } else {
      const float* w = Wb + (o - 5);
      for (int k = s * 128; k < s * 128 + 128; ++k) a = fmaf(hrow[k], w[(size_t)k * 20], a);
    }
    part[o][s] = a;
  }
  __syncthreads();
  if (tid < 25) {
    float a = ((part[tid][0] + part[tid][1]) + (part[tid][2] + part[tid][3]))
            + ((part[tid][4] + part[tid][5]) + (part[tid][6] + part[tid][7]));
    a += (tid < 5) ? bcv[tid] : bbv[tid - 5];
    outv[tid] = a;
  }
  __syncthreads();
  if (tid == 0) {
    float m = outv[0];
    for (int c = 1; c < 5; ++c) m = fmaxf(m, outv[c]);
    float e[5], ssum = 0.f;
    for (int c = 0; c < 5; ++c) { e[c] = expf(outv[c] - m); ssum += e[c]; }
    for (int c = 0; c < 5; ++c) smax[c] = e[c] / ssum;
  }
  __syncthreads();
  if (tid < 4) {
    const int c = tid + 1;
    const float* pr = props + (size_t)n * 4;
    const float x1 = pr[0], y1 = pr[1], x2 = pr[2], y2 = pr[3];
    const float w = x2 - x1, h = y2 - y1;
    const float cx = x1 + 0.5f * w, cy = y1 + 0.5f * h;
    const float r0 = outv[5 + c * 4 + 0], r1 = outv[5 + c * 4 + 1];
    const float r2 = outv[5 + c * 4 + 2], r3 = outv[5 + c * 4 + 3];
    const float dx = r0 / 10.0f, dy = r1 / 10.0f;
    const float dw = fminf(r2 / 5.0f, BBOX_CLIP_F);
    const float dh = fminf(r3 / 5.0f, BBOX_CLIP_F);
    const float pcx = dx * w + cx, pcy = dy * h + cy;
    const float pw = expf(dw) * w, ph = expf(dh) * h;
    float bx1 = pcx - 0.5f * pw, by1 = pcy - 0.5f * ph;
    float bx2 = pcx + 0.5f * pw, by2 = pcy + 0.5f * ph;
    bx1 = fminf(fmaxf(bx1, 0.f), 800.f);
    by1 = fminf(fmaxf(by1, 0.f), 800.f);
    bx2 = fminf(fmaxf(bx2, 0.f), 800.f);
    by2 = fminf(fmaxf(by2, 0.f), 800.f);
    const int img = n >> 9;
    const int pidx = ((n & 511) << 2) + (c - 1);
    float* o = pb + (size_t)(img * NDET + pidx) * 4;
    o[0] = bx1; o[1] = by1; o[2] = bx2; o[3] = by2;
    sc[img * NDET + pidx] = smax[c];
  }
}

// Stable descending sort of 2048 scores per image (bitonic on u64 composite key)
__global__ __launch_bounds__(1024) void sort_kernel(
    const float* __restrict__ sc, unsigned* __restrict__ sidx) {
  const int b = blockIdx.x;
  __shared__ unsigned long long key[NDET];
  const int tid = threadIdx.x;
  for (int t = tid; t < NDET; t += 1024) {
    unsigned bits = __float_as_uint(sc[b * NDET + t]);
    key[t] = ((unsigned long long)bits << 32) | (unsigned)(~t);
  }
  __syncthreads();
  for (int k = 2; k <= NDET; k <<= 1) {
    for (int j = k >> 1; j > 0; j >>= 1) {
      for (int t = tid; t < NDET; t += 1024) {
        const int ixj = t ^ j;
        if (ixj > t) {
          const bool up = (t & k) == 0;
          unsigned long long a = key[t], bb_ = key[ixj];
          if ((a < bb_) == up) { key[t] = bb_; key[ixj] = a; }
        }
      }
      __syncthreads();
    }
  }
  for (int t = tid; t < NDET; t += 1024)
    sidx[b * NDET + t] = ~(unsigned)key[t];
}

__global__ __launch_bounds__(256) void prep_kernel(
    const unsigned* __restrict__ sidx, const float* __restrict__ pb, const float* __restrict__ sc,
    float* __restrict__ sbox, float* __restrict__ soff, float* __restrict__ sscore,
    float* __restrict__ sarea, float* __restrict__ slab, unsigned* __restrict__ vword) {
  const int b = blockIdx.y;
  const int i = blockIdx.x * 256 + threadIdx.x;
  const unsigned oi = sidx[b * NDET + i];
  const float* bx = pb + (size_t)(b * NDET + oi) * 4;
  const float x1 = bx[0], y1 = bx[1], x2 = bx[2], y2 = bx[3];
  const float s = sc[b * NDET + oi];
  const float lab = (float)((oi & 3) + 1);
  const bool valid = (s > 0.05f) && ((x2 - x1) >= 0.01f) && ((y2 - y1) >= 0.01f);
  const float off = lab * 801.0f;
  float* sb = sbox + (size_t)(b * NDET + i) * 4;
  sb[0] = x1; sb[1] = y1; sb[2] = x2; sb[3] = y2;
  float* so = soff + (size_t)(b * NDET + i) * 4;
  so[0] = x1 + off; so[1] = y1 + off; so[2] = x2 + off; so[3] = y2 + off;
  sscore[b * NDET + i] = s;
  sarea[b * NDET + i] = (x2 - x1) * (y2 - y1);
  slab[b * NDET + i] = lab;
  const unsigned long long bal = __ballot(valid);
  if ((i & 31) == 0) vword[b * 64 + (i >> 5)] = (unsigned)(bal >> (i & 32));
}

__global__ __launch_bounds__(256) void mask_kernel(
    const float* __restrict__ soff, const float* __restrict__ sarea,
    unsigned* __restrict__ mask) {
  const int b = blockIdx.y;
  __shared__ float box[NDET][4];
  __shared__ float area[NDET];
  const int tid = threadIdx.x;
  const float4* src = (const float4*)(soff + (size_t)b * NDET * 4);
  for (int t = tid; t < NDET; t += 256) ((float4*)box)[t] = src[t];
  const float4* asrc = (const float4*)(sarea + (size_t)b * NDET);
  for (int t = tid; t < NDET / 4; t += 256) ((float4*)area)[t] = asrc[t];
  __syncthreads();
  const int li = tid >> 6;
  const int w  = tid & 63;
  const int i  = blockIdx.x * 4 + li;
  const float ax1 = box[i][0], ay1 = box[i][1], ax2 = box[i][2], ay2 = box[i][3];
  const float aa = area[i];
  unsigned bits = 0;
#pragma unroll 4
  for (int jj = 0; jj < 32; ++jj) {
    const int j = jj * 64 + w;
    const float ix = fmaxf(fminf(ax2, box[j][2]) - fmaxf(ax1, box[j][0]), 0.f);
    const float iy = fmaxf(fminf(ay2, box[j][3]) - fmaxf(ay1, box[j][1]), 0.f);
    const float inter = ix * iy;
    const float iou = inter / (aa + area[j] - inter + 1e-9f);
    if (j > i && iou > 0.5f) bits |= (1u << jj);
  }
  mask[((size_t)b * NDET + i) * 64 + w] = bits;
}

__global__ __launch_bounds__(64) void scan_kernel(
    const unsigned* __restrict__ vword, const unsigned* __restrict__ mask,
    const float* __restrict__ sbox, const float* __restrict__ sscore,
    const float* __restrict__ slab, float* __restrict__ out) {
  const int b = blockIdx.x;
  const int lane = threadIdx.x;
  const unsigned valid = vword[b * 64 + lane];
  unsigned sup = 0;
  __shared__ unsigned short klist[DETS];
  int kcnt = 0;
  for (int i = 0; i < NDET; ++i) {
    const unsigned v = __shfl(valid, i >> 5);
    if (!((v >> (i & 31)) & 1)) continue;
    const unsigned s = __shfl(sup, i & 63);
    if ((s >> (i >> 6)) & 1) continue;
    if (lane == 0) klist[kcnt] = (unsigned short)i;
    kcnt++;
    sup |= mask[((size_t)b * NDET + i) * 64 + lane];
    if (kcnt == DETS) break;
  }
  __syncthreads();
  for (int s = lane; s < DETS; s += 64) {
    float b0 = 0.f, b1 = 0.f, b2 = 0.f, b3 = 0.f, sv = 0.f, lv = 0.f;
    if (s < kcnt) {
      const int i = klist[s];
      const float* bx = sbox + ((size_t)b * NDET + i) * 4;
      b0 = bx[0]; b1 = bx[1]; b2 = bx[2]; b3 = bx[3];
      sv = sscore[b * NDET + i];
      lv = slab[b * NDET + i];
    }
    float* ob = out + ((size_t)b * DETS + s) * 4;
    ob[0] = b0; ob[1] = b1; ob[2] = b2; ob[3] = b3;
    out[2 * DETS * 4 + b * DETS + s] = sv;
    out[2 * DETS * 4 + 2 * DETS + b * DETS + s] = lv;
  }
}

extern "C" void kernel_launch(void* const* d_in, const int* in_sizes, int n_in,
                              void* d_out, int out_size, void* d_ws, size_t ws_size,
                              hipStream_t stream) {
  const float* X     = (const float*)d_in[0];
  const float* props = (const float*)d_in[1];
  const float* W1    = (const float*)d_in[2];
  const float* b1    = (const float*)d_in[3];
  const float* W2    = (const float*)d_in[4];
  const float* b2    = (const float*)d_in[5];
  const float* Wc    = (const float*)d_in[6];
  const float* bc    = (const float*)d_in[7];
  const float* Wb    = (const float*)d_in[8];
  const float* bb    = (const float*)d_in[9];
  float* out = (float*)d_out;

  // ---- MFMA-path workspace need: T(8 slices) + H1 + H2 + WT(h,l) + W2T(h,l) + post ----
  const size_t NEED_MFMA =
      (size_t)(8 + 1 + 1) * 1048576 * 4 +                     // T, H1, H2 (fp32)
      (size_t)2 * (size_t)K1 * 1024 * 2 +                     // WTh, WTl
      (size_t)2 * 1048576 * 2 +                               // W2Th, W2Tl
      (size_t)2500000;                                        // post-process buffers (~2.4MB)

  float *T, *H1, *H2, *pb, *sc;
  unsigned short *WTh = nullptr, *WTl = nullptr, *W2Th = nullptr, *W2Tl = nullptr;
  const bool use_mfma = (ws_size >= NEED_MFMA);
  if (use_mfma) {
    T   = (float*)d_ws;                  // 8 * 1048576
    H1  = T + 8 * 1048576;
    H2  = H1 + 1048576;
    WTh = (unsigned short*)(H2 + 1048576);
    WTl = WTh + (size_t)K1 * 1024;
    W2Th = WTl + (size_t)K1 * 1024;
    W2Tl = W2Th + 1048576;
    pb  = (float*)(W2Tl + 1048576);
  } else {
    T  = (float*)d_ws;                   // 4 * 1048576
    H1 = T + 4 * 1048576;
    H2 = H1 + 1048576;
    pb = H2 + 1048576;
  }
  sc = pb + 2 * NDET * 4;
  unsigned* sidx = (unsigned*)(sc + 2 * NDET);
  float* sbox   = (float*)(sidx + 2 * NDET);
  float* soff   = sbox + 2 * NDET * 4;
  float* sscore = soff + 2 * NDET * 4;
  float* sarea  = sscore + 2 * NDET;
  float* slab   = sarea + 2 * NDET;
  unsigned* vword = (unsigned*)(slab + 2 * NDET);
  unsigned* mask  = vword + 128;

  if (use_mfma) {
    // weight transpose+convert (W[K][N] -> WT{h,l}[N][K] bf16)
    transpose_bf16<<<dim3(K1 / 32, 32), 256, 0, stream>>>(W1, WTh, WTl, K1, REP);
    transpose_bf16<<<dim3(32, 32), 256, 0, stream>>>(W2, W2Th, W2Tl, REP, REP);
    // GEMM1: M=N=1024, K=12544, splitK=8 (49 k-steps each)
    gemm_mfma<<<dim3(8, 8, 8), 256, 0, stream>>>(X, WTh, WTl, T, K1, 49);
    combine8_relu<<<1024, 256, 0, stream>>>(T, b1, H1);
    // GEMM2: 1024^3, splitK=4 (8 k-steps each)
    gemm_mfma<<<dim3(8, 8, 4), 256, 0, stream>>>(H1, W2Th, W2Tl, T, REP, 8);
    combine_relu<<<1024, 256, 0, stream>>>(T, b2, H2);
  } else {
    gemm64<<<dim3(16, 16, 4), 256, 0, stream>>>(X, W1, T, K1, REP, K1 / 4);
    combine_relu<<<1024, 256, 0, stream>>>(T, b1, H1);
    gemm64<<<dim3(16, 16, 4), 256, 0, stream>>>(H1, W2, T, REP, REP, REP / 4);
    combine_relu<<<1024, 256, 0, stream>>>(T, b2, H2);
  }
  heads_kernel<<<1024, 256, 0, stream>>>(H2, Wc, bc, Wb, bb, props, pb, sc);
  sort_kernel<<<2, 1024, 0, stream>>>(sc, sidx);
  prep_kernel<<<dim3(8, 2), 256, 0, stream>>>(sidx, pb, sc, sbox, soff, sscore, sarea, slab, vword);
  mask_kernel<<<dim3(512, 2), 256, 0, stream>>>(soff, sarea, mask);
  scan_kernel<<<2, 64, 0, stream>>>(vword, mask, sbox, sscore, slab, out);
}